// Round 6
// baseline (319.638 us; speedup 1.0000x reference)
//
#include <hip/hip_runtime.h>
#include <stdint.h>

#define N_NODES 10000
#define N_EDGES 160000
#define D 512
#define TOT (N_NODES * D)          // 5,120,000
#define M_PAD 10112                // 79 * 128, GEMM M coverage

typedef _Float16 h8 __attribute__((ext_vector_type(8)));
typedef float f4 __attribute__((ext_vector_type(4)));

// ---------------- threefry2x32 (JAX partitionable semantics) ----------------
__host__ __device__ inline uint32_t rotl32(uint32_t v, int r) {
    return (v << r) | (v >> (32 - r));
}

__host__ __device__ inline void tf2x32(uint32_t k0, uint32_t k1,
                                       uint32_t& x0, uint32_t& x1) {
    uint32_t k2 = k0 ^ k1 ^ 0x1BD11BDAu;
    x0 += k0; x1 += k1;
    x0 += x1; x1 = rotl32(x1, 13); x1 ^= x0;
    x0 += x1; x1 = rotl32(x1, 15); x1 ^= x0;
    x0 += x1; x1 = rotl32(x1, 26); x1 ^= x0;
    x0 += x1; x1 = rotl32(x1,  6); x1 ^= x0;
    x0 += k1; x1 += k2 + 1u;
    x0 += x1; x1 = rotl32(x1, 17); x1 ^= x0;
    x0 += x1; x1 = rotl32(x1, 29); x1 ^= x0;
    x0 += x1; x1 = rotl32(x1, 16); x1 ^= x0;
    x0 += x1; x1 = rotl32(x1, 24); x1 ^= x0;
    x0 += k2; x1 += k0 + 2u;
    x0 += x1; x1 = rotl32(x1, 13); x1 ^= x0;
    x0 += x1; x1 = rotl32(x1, 15); x1 ^= x0;
    x0 += x1; x1 = rotl32(x1, 26); x1 ^= x0;
    x0 += x1; x1 = rotl32(x1,  6); x1 ^= x0;
    x0 += k0; x1 += k1 + 3u;
    x0 += x1; x1 = rotl32(x1, 17); x1 ^= x0;
    x0 += x1; x1 = rotl32(x1, 29); x1 ^= x0;
    x0 += x1; x1 = rotl32(x1, 16); x1 ^= x0;
    x0 += x1; x1 = rotl32(x1, 24); x1 ^= x0;
    x0 += k1; x1 += k2 + 4u;
    x0 += x1; x1 = rotl32(x1, 13); x1 ^= x0;
    x0 += x1; x1 = rotl32(x1, 15); x1 ^= x0;
    x0 += x1; x1 = rotl32(x1, 26); x1 ^= x0;
    x0 += x1; x1 = rotl32(x1,  6); x1 ^= x0;
    x0 += k2; x1 += k0 + 5u;
}

__device__ __forceinline__ float dropout_gate(uint32_t k0, uint32_t k1, uint32_t j) {
    uint32_t c0 = 0u, c1 = j;
    tf2x32(k0, k1, c0, c1);
    uint32_t bits = c0 ^ c1;
    float u = __uint_as_float((bits >> 9) | 0x3f800000u) - 1.0f;
    return (u < 0.8f) ? 1.0f : 0.0f;
}

// ---------------- degree histogram ----------------
__global__ void hist_kernel(const int* __restrict__ src, const int* __restrict__ dst,
                            int* __restrict__ deg_out, int* __restrict__ deg_in) {
    int e = blockIdx.x * 256 + threadIdx.x;
    if (e >= N_EDGES) return;
    atomicAdd(&deg_out[src[e]], 1);
    atomicAdd(&deg_in[dst[e]], 1);
}

// ---------------- scan (wave-shuffle based) + norm factors ----------------
__global__ __launch_bounds__(1024)
void scan_kernel(const int* __restrict__ deg_in, const int* __restrict__ deg_out,
                 int* __restrict__ row_ptr,
                 float* __restrict__ rn_in, float* __restrict__ rn_out) {
    __shared__ int wsum[16];
    __shared__ int base_s;
    int tid = threadIdx.x;
    int lane = tid & 63, wv = tid >> 6;
    if (tid == 0) base_s = 0;
    __syncthreads();
    for (int start = 0; start < N_NODES; start += 1024) {
        int i = start + tid;
        int v = (i < N_NODES) ? deg_in[i] : 0;
        int s = v;
#pragma unroll
        for (int off = 1; off < 64; off <<= 1) {
            int t = __shfl_up(s, off, 64);
            if (lane >= off) s += t;
        }
        if (lane == 63) wsum[wv] = s;
        __syncthreads();
        if (wv == 0 && lane < 16) {
            int ws = wsum[lane];
#pragma unroll
            for (int off = 1; off < 16; off <<= 1) {
                int t = __shfl_up(ws, off, 64);
                if (lane >= off) ws += t;
            }
            wsum[lane] = ws;
        }
        __syncthreads();
        if (i < N_NODES) {
            int prefix = base_s + ((wv > 0) ? wsum[wv - 1] : 0) + (s - v);
            row_ptr[i] = prefix;
            rn_in[i]  = 1.0f / sqrtf(fmaxf((float)v, 1.0f));
            rn_out[i] = 1.0f / sqrtf(fmaxf((float)deg_out[i], 1.0f));
        }
        __syncthreads();
        if (tid == 0) base_s += wsum[15];
        __syncthreads();
    }
    if (tid == 0) row_ptr[N_NODES] = base_s;
}

// ---------------- CSR fill (edges grouped by dst, packed {src, w_bits}) -----
__global__ void fill_kernel(const int* __restrict__ src, const int* __restrict__ dst,
                            const float* __restrict__ ew, const int* __restrict__ row_ptr,
                            int* __restrict__ cursor, int2* __restrict__ csr) {
    int e = blockIdx.x * 256 + threadIdx.x;
    if (e >= N_EDGES) return;
    int v = dst[e];
    int pos = atomicAdd(&cursor[v], 1);
    int idx = row_ptr[v] + pos;
    csr[idx] = make_int2(src[e], __float_as_int(ew[e]));
}

// ---------------- W fp32 [K][N] -> Wt fp16 [N][K] (LDS tile transpose) ------
__global__ __launch_bounds__(256)
void wconvert_kernel(const float* __restrict__ W0, const float* __restrict__ W1,
                     const float* __restrict__ W2, _Float16* __restrict__ Wt) {
    __shared__ float tile[64][65];
    const float* W = (blockIdx.z == 0) ? W0 : (blockIdx.z == 1) ? W1 : W2;
    _Float16* T = Wt + (size_t)blockIdx.z * 512 * 512;
    int r0 = blockIdx.y * 64, c0 = blockIdx.x * 64;
    int t = threadIdx.x;
    int c = t & 63, rq = t >> 6;
#pragma unroll
    for (int i = 0; i < 16; ++i) {
        int r = rq + i * 4;
        tile[r][c] = W[(size_t)(r0 + r) * 512 + c0 + c];
    }
    __syncthreads();
    int k = t & 63, nq = t >> 6;
#pragma unroll
    for (int i = 0; i < 16; ++i) {
        int n = nq + i * 4;
        T[(size_t)(c0 + n) * 512 + r0 + k] = (_Float16)tile[k][n];
    }
}

// ---------------- dropout (fp32 in): h -> y fp16 (mask + /0.8 + src-norm) ---
__global__ __launch_bounds__(256)
void dropout_kernel(const float* __restrict__ x, _Float16* __restrict__ y,
                    const float* __restrict__ rn_out, uint32_t k0, uint32_t k1) {
    int t = blockIdx.x * 256 + threadIdx.x;
    int j = t * 4;
    if (j >= TOT) return;
    float4 xv = *(const float4*)&x[j];
    float w = rn_out[j >> 9];
    _Float16 r[4];
    uint32_t jj = (uint32_t)j;
#pragma unroll
    for (int i = 0; i < 4; ++i) {
        float g = dropout_gate(k0, k1, jj + (uint32_t)i);
        float xi = (&xv.x)[i];
        r[i] = (_Float16)(g * (xi / 0.8f) * w);
    }
    *(ushort4*)&y[j] = *(ushort4*)r;
}

// ---------------- dropout (fp16 in): y' -> y fp16, full-occupancy threefry --
__global__ __launch_bounds__(256)
void dropout16_kernel(const _Float16* __restrict__ x, _Float16* __restrict__ y,
                      const float* __restrict__ rn_out, uint32_t k0, uint32_t k1) {
    int t = blockIdx.x * 256 + threadIdx.x;
    int j = t * 8;
    if (j >= TOT) return;
    h8 xv = *(const h8*)&x[j];
    float w = rn_out[j >> 9];
    _Float16 r[8];
    uint32_t jj = (uint32_t)j;
#pragma unroll
    for (int i = 0; i < 8; ++i) {
        float g = dropout_gate(k0, k1, jj + (uint32_t)i);
        r[i] = (_Float16)(g * ((float)xv[i] / 0.8f) * w);
    }
    *(h8*)&y[j] = *(h8*)r;
}

// ---------------- aggregate: agg[v,:] = sum_e w_e * y[src_e,:] --------------
// 1 wave per node, 8-edge unroll for outstanding-load depth.
__global__ __launch_bounds__(256)
void aggregate_kernel(const _Float16* __restrict__ y, const int* __restrict__ row_ptr,
                      const int2* __restrict__ csr, _Float16* __restrict__ agg) {
    int node = blockIdx.x * 4 + (threadIdx.x >> 6);
    int lane = threadIdx.x & 63;
    if (node >= N_NODES) return;
    int beg = row_ptr[node], end = row_ptr[node + 1];
    float acc[8] = {0, 0, 0, 0, 0, 0, 0, 0};
    int k = beg;
    for (; k + 7 < end; k += 8) {
        h8 a[8];
        float w[8];
#pragma unroll
        for (int q = 0; q < 8; ++q) {
            int2 e = csr[k + q];
            a[q] = *(const h8*)&y[(size_t)e.x * 512 + lane * 8];
            w[q] = __int_as_float(e.y);
        }
#pragma unroll
        for (int q = 0; q < 8; ++q)
#pragma unroll
            for (int i = 0; i < 8; ++i) acc[i] += w[q] * (float)a[q][i];
    }
    for (; k + 3 < end; k += 4) {
        h8 a[4];
        float w[4];
#pragma unroll
        for (int q = 0; q < 4; ++q) {
            int2 e = csr[k + q];
            a[q] = *(const h8*)&y[(size_t)e.x * 512 + lane * 8];
            w[q] = __int_as_float(e.y);
        }
#pragma unroll
        for (int q = 0; q < 4; ++q)
#pragma unroll
            for (int i = 0; i < 8; ++i) acc[i] += w[q] * (float)a[q][i];
    }
    for (; k < end; ++k) {
        int2 e0 = csr[k];
        float w0 = __int_as_float(e0.y);
        h8 a = *(const h8*)&y[(size_t)e0.x * 512 + lane * 8];
#pragma unroll
        for (int i = 0; i < 8; ++i) acc[i] += w0 * (float)a[i];
    }
    _Float16 r[8];
#pragma unroll
    for (int i = 0; i < 8; ++i) r[i] = (_Float16)acc[i];
    *(h8*)&agg[(size_t)node * 512 + lane * 8] = *(h8*)r;
}

// ---------------- fp16 MFMA GEMM, tile 128x64, BK=32 ------------------------
// A staged via padded LDS (2-way-only bank aliasing = free); B fragments
// loaded DIRECTLY from global (Wt is 512 KB, L2-resident; same index math as
// the old LDS read -> bit-identical). Register prefetch 1 tile deep.
// Epilogue: *rn_in + bias, then mode 0: ELU -> fp16 y' (dropout is a separate
// full-occupancy pass); mode 1: plain -> fp32 out.
#define GBK 32
#define LDA 40
__global__ __launch_bounds__(256)
void gemm_kernel(const _Float16* __restrict__ A, const _Float16* __restrict__ Wt,
                 const float* __restrict__ bias, const float* __restrict__ rn_in,
                 _Float16* __restrict__ yout, float* __restrict__ fout, int mode) {
    __shared__ _Float16 As[128 * LDA];   // 10 KB
    int tid = threadIdx.x;
    int wv = tid >> 6, lane = tid & 63;

    // XCD-aware tile swizzle: xcd ~ f&7 owns a contiguous tile range.
    int f = blockIdx.x + blockIdx.y * 8;
    int T = (f & 7) * 79 + (f >> 3);
    int row0 = (T >> 3) * 128, col0 = (T & 7) * 64;

    int wr = wv >> 1, wc = wv & 1;       // 2x2 wave grid: 64 rows x 32 cols each

    f4 acc[4][2];
#pragma unroll
    for (int i = 0; i < 4; ++i)
#pragma unroll
        for (int j = 0; j < 2; ++j) acc[i][j] = (f4){0.f, 0.f, 0.f, 0.f};

    // A staging: 128x32 halves = 512 16B-chunks, 2/thread
    int srow = tid >> 2;                 // 0..63
    int sseg = (tid & 3) * 8;            // k offset in halves
    const _Float16* gA0 = A + (size_t)(row0 + srow) * 512 + sseg;
    const _Float16* gA1 = gA0 + (size_t)64 * 512;
    _Float16* wA0 = &As[srow * LDA + sseg];
    _Float16* wA1 = &As[(64 + srow) * LDA + sseg];

    int kf = (lane >> 4) * 8;            // k-chunk per quad
    const _Float16* fa = &As[(wr * 64 + (lane & 15)) * LDA + kf];
    // B direct-from-global fragment pointers (nt = 0,1)
    const _Float16* gB0 = Wt + (size_t)(col0 + wc * 32 + (lane & 15)) * 512 + kf;
    const _Float16* gB1 = gB0 + (size_t)16 * 512;

    h8 ra0 = *(const h8*)gA0;
    h8 ra1 = *(const h8*)gA1;
    h8 rb0 = *(const h8*)gB0;
    h8 rb1 = *(const h8*)gB1;

    for (int kk = 0; kk < 512; kk += GBK) {
        *(h8*)wA0 = ra0;
        *(h8*)wA1 = ra1;
        h8 bf0 = rb0, bf1 = rb1;
        __syncthreads();
        if (kk + GBK < 512) {            // prefetch next tile into registers
            ra0 = *(const h8*)(gA0 + kk + GBK);
            ra1 = *(const h8*)(gA1 + kk + GBK);
            rb0 = *(const h8*)(gB0 + kk + GBK);
            rb1 = *(const h8*)(gB1 + kk + GBK);
        }
        h8 af[4];
#pragma unroll
        for (int mt = 0; mt < 4; ++mt) af[mt] = *(const h8*)(fa + mt * 16 * LDA);
#pragma unroll
        for (int mt = 0; mt < 4; ++mt) {
            acc[mt][0] = __builtin_amdgcn_mfma_f32_16x16x32_f16(af[mt], bf0,
                                                                acc[mt][0], 0, 0, 0);
            acc[mt][1] = __builtin_amdgcn_mfma_f32_16x16x32_f16(af[mt], bf1,
                                                                acc[mt][1], 0, 0, 0);
        }
        __syncthreads();
    }

    // epilogue. C/D layout: col = lane&15, row = (lane>>4)*4 + reg
    int mbase = row0 + wr * 64;
    int nbase = col0 + wc * 32;
#pragma unroll
    for (int mt = 0; mt < 4; ++mt) {
#pragma unroll
        for (int nt = 0; nt < 2; ++nt) {
            int gr0 = mbase + mt * 16 + (lane >> 4) * 4;
            int gc = nbase + nt * 16 + (lane & 15);
            float bcol = bias[gc];
#pragma unroll
            for (int i = 0; i < 4; ++i) {
                int gr = gr0 + i;
                if (gr >= N_NODES) continue;
                float v = acc[mt][nt][i] * rn_in[gr] + bcol;
                if (mode == 0) {
                    v = (v > 0.f) ? v : expm1f(v);
                    yout[(size_t)gr * 512 + gc] = (_Float16)v;
                } else {
                    fout[(size_t)gr * 512 + gc] = v;
                }
            }
        }
    }
}

// ---------------- launch ----------------
extern "C" void kernel_launch(void* const* d_in, const int* in_sizes, int n_in,
                              void* d_out, int out_size, void* d_ws, size_t ws_size,
                              hipStream_t stream) {
    const float* h   = (const float*)d_in[0];
    const int*   src = (const int*)d_in[1];
    const int*   dst = (const int*)d_in[2];
    const float* ew  = (const float*)d_in[3];
    const float* W0  = (const float*)d_in[4];
    const float* b0  = (const float*)d_in[5];
    const float* W1  = (const float*)d_in[6];
    const float* b1  = (const float*)d_in[7];
    const float* W2  = (const float*)d_in[8];
    const float* b2  = (const float*)d_in[9];
    const float* bl[3] = {b0, b1, b2};
    float* out = (float*)d_out;

    char* ws = (char*)d_ws;
    _Float16* y16  = (_Float16*)ws; ws += (size_t)TOT * 2;            // 10.24 MB
    _Float16* yPre = (_Float16*)ws; ws += (size_t)TOT * 2;            // 10.24 MB
    _Float16* aggF = (_Float16*)ws; ws += (size_t)M_PAD * 512 * 2;    // 10.35 MB
    _Float16* Wt   = (_Float16*)ws; ws += (size_t)3 * 512 * 512 * 2;  // 1.57 MB
    // the next three must stay contiguous: zeroed with ONE memset
    int* degi_in  = (int*)ws;  ws += N_NODES * 4;
    int* degi_out = (int*)ws;  ws += N_NODES * 4;
    int* cursor   = (int*)ws;  ws += N_NODES * 4;
    int* row_ptr  = (int*)ws;  ws += (N_NODES + 1) * 4;
    ws = (char*)(((uintptr_t)ws + 15) & ~(uintptr_t)15);
    int2* csr     = (int2*)ws; ws += (size_t)N_EDGES * 8;
    float* rn_in  = (float*)ws; ws += N_NODES * 4;
    float* rn_out = (float*)ws; ws += N_NODES * 4;

    hipMemsetAsync(degi_in, 0, 3 * N_NODES * 4, stream);

    hist_kernel<<<(N_EDGES + 255) / 256, 256, 0, stream>>>(src, dst, degi_out, degi_in);
    scan_kernel<<<1, 1024, 0, stream>>>(degi_in, degi_out, row_ptr, rn_in, rn_out);
    fill_kernel<<<(N_EDGES + 255) / 256, 256, 0, stream>>>(src, dst, ew, row_ptr,
                                                           cursor, csr);
    wconvert_kernel<<<dim3(8, 8, 3), 256, 0, stream>>>(W0, W1, W2, Wt);

    // partitionable split: subkey i = both lanes of cipher(key=(0,42), x0=0, x1=i)
    uint32_t dk[3][2];
    for (int i = 0; i < 3; ++i) {
        uint32_t c0 = 0u, c1 = (uint32_t)i;
        tf2x32(0u, 42u, c0, c1);
        dk[i][0] = c0; dk[i][1] = c1;
    }

    dropout_kernel<<<(TOT / 4 + 255) / 256, 256, 0, stream>>>(h, y16, rn_out,
                                                              dk[0][0], dk[0][1]);
    for (int l = 0; l < 3; ++l) {
        aggregate_kernel<<<N_NODES / 4, 256, 0, stream>>>(y16, row_ptr, csr, aggF);
        int mode = (l < 2) ? 0 : 1;
        gemm_kernel<<<dim3(8, M_PAD / 128), 256, 0, stream>>>(
            aggF, Wt + (size_t)l * 512 * 512, bl[l], rn_in, yPre, out, mode);
        if (l < 2) {
            dropout16_kernel<<<TOT / 8 / 256, 256, 0, stream>>>(
                yPre, y16, rn_out, dk[l + 1][0], dk[l + 1][1]);
        }
    }
}